// Round 1
// baseline (622.902 us; speedup 1.0000x reference)
//
#include <hip/hip_runtime.h>

#define N_NODES 50000
#define N_EDGES 800000
#define IN_F 96
#define HID_F 128
#define OUT_F 64
#define T_S 8

typedef __attribute__((ext_vector_type(8))) short short8;
typedef __attribute__((ext_vector_type(4))) float float4v;

__device__ __forceinline__ float bf2f(unsigned short h) {
    unsigned u = ((unsigned)h) << 16;
    float f;
    __builtin_memcpy(&f, &u, 4);
    return f;
}
__device__ __forceinline__ unsigned short f2bf(float f) {
    unsigned u;
    __builtin_memcpy(&u, &f, 4);
    unsigned r = (u + 0x7fffu + ((u >> 16) & 1u)) >> 16;  // RTNE
    return (unsigned short)r;
}

// ---------------- CSR build ----------------
__global__ void k_count(const int* __restrict__ dst, int* __restrict__ cnt) {
    int e = blockIdx.x * 256 + threadIdx.x;
    if (e < N_EDGES) atomicAdd(&cnt[dst[e]], 1);
}

__global__ void k_scan(const int* __restrict__ cnt, int* __restrict__ row_ptr,
                       int* __restrict__ cursor) {
    __shared__ int buf[1024];
    const int CH = 49;  // 1024*49 = 50176 >= 50000
    int tid = threadIdx.x;
    int base = tid * CH;
    int s = 0;
    for (int i = 0; i < CH; i++) {
        int idx = base + i;
        if (idx < N_NODES) s += cnt[idx];
    }
    buf[tid] = s;
    __syncthreads();
    for (int off = 1; off < 1024; off <<= 1) {
        int v = buf[tid];
        if (tid >= off) v += buf[tid - off];
        __syncthreads();
        buf[tid] = v;
        __syncthreads();
    }
    int p = (tid == 0) ? 0 : buf[tid - 1];  // exclusive prefix
    for (int i = 0; i < CH; i++) {
        int idx = base + i;
        if (idx < N_NODES) {
            row_ptr[idx] = p;
            cursor[idx] = p;
            p += cnt[idx];
        }
    }
    if (tid == 0) row_ptr[N_NODES] = N_EDGES;
}

__global__ void k_fill(const int* __restrict__ src, const int* __restrict__ dst,
                       const float* __restrict__ ew, int* __restrict__ cursor,
                       int* __restrict__ csr_src, float* __restrict__ csr_w) {
    int e = blockIdx.x * 256 + threadIdx.x;
    if (e < N_EDGES) {
        int d = dst[e];
        int pos = atomicAdd(&cursor[d], 1);
        csr_src[pos] = src[e];
        csr_w[pos] = ew[e];
    }
}

// ---------------- SPMM1: agg1 = spmm(x), stored bf16 [N][96] ----------------
__global__ __launch_bounds__(256) void k_spmm1(const float* __restrict__ x,
                                               const int* __restrict__ row_ptr,
                                               const int* __restrict__ csr_src,
                                               const float* __restrict__ csr_w,
                                               unsigned short* __restrict__ agg1) {
    int sub = threadIdx.x >> 7;  // 0..1
    int f = threadIdx.x & 127;
    int node = blockIdx.x * 2 + sub;
    if (node >= N_NODES || f >= IN_F) return;
    int beg = row_ptr[node], end = row_ptr[node + 1];
    float a0 = 0.f, a1 = 0.f, a2 = 0.f, a3 = 0.f;
    int e = beg;
    for (; e + 3 < end; e += 4) {
        int s0 = csr_src[e], s1 = csr_src[e + 1], s2 = csr_src[e + 2], s3 = csr_src[e + 3];
        float w0 = csr_w[e], w1 = csr_w[e + 1], w2 = csr_w[e + 2], w3 = csr_w[e + 3];
        a0 += w0 * x[(size_t)s0 * IN_F + f];
        a1 += w1 * x[(size_t)s1 * IN_F + f];
        a2 += w2 * x[(size_t)s2 * IN_F + f];
        a3 += w3 * x[(size_t)s3 * IN_F + f];
    }
    for (; e < end; e++) a0 += csr_w[e] * x[(size_t)csr_src[e] * IN_F + f];
    agg1[(size_t)node * IN_F + f] = f2bf(a0 + a1 + a2 + a3);
}

// ------------- Weight prep: masked W1/W2 pre-swizzled into MFMA fragment order -------------
// layout per t (20480 bf16): [0,12288): W1 frags [kk(3)][nt(8)][lane(64)][j(8)]
//                            [12288,20480): W2 frags [kk(4)][ot(4)][lane(64)][j(8)]
// fragment element: feature n = tile*16 + (lane&15), k = kk*32 + (lane>>4)*8 + j
__global__ void k_wprep(const float* __restrict__ W1, const float* __restrict__ W2,
                        const float* __restrict__ m1, const float* __restrict__ m2,
                        unsigned short* __restrict__ wf) {
    int gid = blockIdx.x * 256 + threadIdx.x;  // 8*20480 = 163840 total
    if (gid >= T_S * 20480) return;
    int t = gid / 20480;
    int idx = gid % 20480;
    float val;
    if (idx < 12288) {
        int j = idx & 7, lane = (idx >> 3) & 63, fr = idx >> 9;  // fr 0..23
        int kk = fr >> 3, nt = fr & 7;
        int k = kk * 32 + (lane >> 4) * 8 + j;
        int n = nt * 16 + (lane & 15);
        val = W1[k * HID_F + n] * m1[((size_t)t * IN_F + k) * HID_F + n];
    } else {
        int i2 = idx - 12288;
        int j = i2 & 7, lane = (i2 >> 3) & 63, fr = i2 >> 9;  // fr 0..15
        int kk = fr >> 2, ot = fr & 3;
        int k = kk * 32 + (lane >> 4) * 8 + j;
        int o = ot * 16 + (lane & 15);
        val = W2[k * OUT_F + o] * m2[((size_t)t * HID_F + k) * OUT_F + o];
    }
    wf[gid] = f2bf(val);
}

// ------------- Fused GEMM: p_t = relu(agg1 @ W1m_t) @ W2m_t, bf16 out [N][64] -------------
// transposed MFMA orientation: D[m=feature][n=node]; each lane then holds 4 consecutive
// features of ONE node -> packed b64 LDS writes for h, packed 8B global stores for p.
__global__ __launch_bounds__(256) void k_gemm(const unsigned short* __restrict__ agg1,
                                              const unsigned short* __restrict__ wfrags,
                                              unsigned short* __restrict__ P, int tBase) {
    __shared__ __align__(16) unsigned short ldsW[20480];     // 40 KB
    __shared__ __align__(16) unsigned short ldsH[4][2176];   // 4 waves x [16][136] bf16
    int t = tBase + blockIdx.y;
    // cooperative load of this sample's fragments (40960 B = 2560 uint4)
    const uint4* wsrc = (const uint4*)(wfrags + (size_t)t * 20480);
    uint4* wdst = (uint4*)ldsW;
    for (int i = threadIdx.x; i < 2560; i += 256) wdst[i] = wsrc[i];
    __syncthreads();

    int wave = threadIdx.x >> 6, lane = threadIdx.x & 63;
    int quad = lane >> 4, l15 = lane & 15;
    int node = blockIdx.x * 64 + wave * 16 + l15;
    bool v = node < N_NODES;

    // agg1 fragments (B-operand: n = lane&15 = node, k = quad*8+j)
    short8 a[3];
    if (v) {
        const unsigned short* ap = agg1 + (size_t)node * IN_F;
        a[0] = *(const short8*)(ap + 0 * 32 + quad * 8);
        a[1] = *(const short8*)(ap + 1 * 32 + quad * 8);
        a[2] = *(const short8*)(ap + 2 * 32 + quad * 8);
    } else {
        short8 z = {0, 0, 0, 0, 0, 0, 0, 0};
        a[0] = z; a[1] = z; a[2] = z;
    }

    // GEMM1: h[node][hid], lane holds hid = nt*16 + quad*4 + {0..3} for node = node0+l15
    for (int nt = 0; nt < 8; nt++) {
        float4v acc = {0.f, 0.f, 0.f, 0.f};
        for (int kk = 0; kk < 3; kk++) {
            short8 w = *(const short8*)&ldsW[(kk * 8 + nt) * 512 + lane * 8];
            acc = __builtin_amdgcn_mfma_f32_16x16x32_bf16(w, a[kk], acc, 0, 0, 0);
        }
        unsigned h0 = f2bf(fmaxf(acc[0], 0.f));
        unsigned h1 = f2bf(fmaxf(acc[1], 0.f));
        unsigned h2 = f2bf(fmaxf(acc[2], 0.f));
        unsigned h3 = f2bf(fmaxf(acc[3], 0.f));
        uint2 pk;
        pk.x = h0 | (h1 << 16);
        pk.y = h2 | (h3 << 16);
        *(uint2*)&ldsH[wave][l15 * 136 + nt * 16 + quad * 4] = pk;  // b64, conflict-free
    }

    // read back h as fragments (n = l15 = node, k = kk*32 + quad*8 + j) — same-wave LDS, no barrier
    short8 hf[4];
    for (int kk = 0; kk < 4; kk++)
        hf[kk] = *(const short8*)&ldsH[wave][l15 * 136 + kk * 32 + quad * 8];

    // GEMM2: p[node][o], lane holds o = ot*16 + quad*4 + {0..3}
    unsigned short* Pt = P + ((size_t)blockIdx.y * N_NODES + node) * OUT_F;
    for (int ot = 0; ot < 4; ot++) {
        float4v acc = {0.f, 0.f, 0.f, 0.f};
        for (int kk = 0; kk < 4; kk++) {
            short8 w = *(const short8*)&ldsW[12288 + (kk * 4 + ot) * 512 + lane * 8];
            acc = __builtin_amdgcn_mfma_f32_16x16x32_bf16(w, hf[kk], acc, 0, 0, 0);
        }
        if (v) {
            uint2 pk;
            pk.x = (unsigned)f2bf(acc[0]) | ((unsigned)f2bf(acc[1]) << 16);
            pk.y = (unsigned)f2bf(acc[2]) | ((unsigned)f2bf(acc[3]) << 16);
            *(uint2*)(Pt + ot * 16 + quad * 4) = pk;
        }
    }
}

// ------------- SPMM2 (batched over all 8 samples): out[t][n][o] = sum_e w_e * p_t[src][o] -------------
__global__ __launch_bounds__(512) void k_spmm2(const unsigned short* __restrict__ P,
                                               const int* __restrict__ row_ptr,
                                               const int* __restrict__ csr_src,
                                               const float* __restrict__ csr_w,
                                               float* __restrict__ out) {
    int node = blockIdx.x;
    int tt = threadIdx.x >> 6;  // sample
    int o = threadIdx.x & 63;
    int beg = row_ptr[node], end = row_ptr[node + 1];
    const unsigned short* Pt = P + (size_t)tt * N_NODES * OUT_F + o;
    float a0 = 0.f, a1 = 0.f, a2 = 0.f, a3 = 0.f;
    int e = beg;
    for (; e + 3 < end; e += 4) {
        int s0 = csr_src[e], s1 = csr_src[e + 1], s2 = csr_src[e + 2], s3 = csr_src[e + 3];
        float w0 = csr_w[e], w1 = csr_w[e + 1], w2 = csr_w[e + 2], w3 = csr_w[e + 3];
        a0 += w0 * bf2f(Pt[(size_t)s0 * OUT_F]);
        a1 += w1 * bf2f(Pt[(size_t)s1 * OUT_F]);
        a2 += w2 * bf2f(Pt[(size_t)s2 * OUT_F]);
        a3 += w3 * bf2f(Pt[(size_t)s3 * OUT_F]);
    }
    for (; e < end; e++) a0 += csr_w[e] * bf2f(Pt[(size_t)csr_src[e] * OUT_F]);
    out[((size_t)tt * N_NODES + node) * OUT_F + o] = a0 + a1 + a2 + a3;
}

// per-sample fallback (small workspace): 8 nodes per block, one sample
__global__ __launch_bounds__(512) void k_spmm2_1t(const unsigned short* __restrict__ P,
                                                  const int* __restrict__ row_ptr,
                                                  const int* __restrict__ csr_src,
                                                  const float* __restrict__ csr_w,
                                                  float* __restrict__ out) {
    int node = blockIdx.x * 8 + (threadIdx.x >> 6);
    int o = threadIdx.x & 63;
    if (node >= N_NODES) return;
    int beg = row_ptr[node], end = row_ptr[node + 1];
    const unsigned short* Pt = P + o;
    float a0 = 0.f, a1 = 0.f, a2 = 0.f, a3 = 0.f;
    int e = beg;
    for (; e + 3 < end; e += 4) {
        int s0 = csr_src[e], s1 = csr_src[e + 1], s2 = csr_src[e + 2], s3 = csr_src[e + 3];
        float w0 = csr_w[e], w1 = csr_w[e + 1], w2 = csr_w[e + 2], w3 = csr_w[e + 3];
        a0 += w0 * bf2f(Pt[(size_t)s0 * OUT_F]);
        a1 += w1 * bf2f(Pt[(size_t)s1 * OUT_F]);
        a2 += w2 * bf2f(Pt[(size_t)s2 * OUT_F]);
        a3 += w3 * bf2f(Pt[(size_t)s3 * OUT_F]);
    }
    for (; e < end; e++) a0 += csr_w[e] * bf2f(Pt[(size_t)csr_src[e] * OUT_F]);
    out[(size_t)node * OUT_F + o] = a0 + a1 + a2 + a3;
}

extern "C" void kernel_launch(void* const* d_in, const int* in_sizes, int n_in,
                              void* d_out, int out_size, void* d_ws, size_t ws_size,
                              hipStream_t stream) {
    const float* x = (const float*)d_in[0];
    const float* ew = (const float*)d_in[1];
    const float* W1 = (const float*)d_in[2];
    const float* W2 = (const float*)d_in[3];
    const float* m1 = (const float*)d_in[4];
    const float* m2 = (const float*)d_in[5];
    const int* src = (const int*)d_in[6];
    const int* dst = (const int*)d_in[7];
    float* out = (float*)d_out;

    char* w = (char*)d_ws;
    size_t off = 0;
    auto alloc = [&](size_t bytes) -> void* {
        void* p = (void*)(w + off);
        off += (bytes + 255) & ~(size_t)255;
        return p;
    };
    int* cnt = (int*)alloc((size_t)N_NODES * 4);
    int* row_ptr = (int*)alloc((size_t)(N_NODES + 1) * 4);
    int* cursor = (int*)alloc((size_t)N_NODES * 4);
    int* csr_src = (int*)alloc((size_t)N_EDGES * 4);
    float* csr_w = (float*)alloc((size_t)N_EDGES * 4);
    unsigned short* agg1 = (unsigned short*)alloc((size_t)N_NODES * IN_F * 2);
    unsigned short* wf = (unsigned short*)alloc((size_t)T_S * 20480 * 2);
    size_t needBatch = off + (size_t)T_S * N_NODES * OUT_F * 2;
    bool batched = ws_size >= needBatch;
    unsigned short* P = (unsigned short*)alloc(
        batched ? (size_t)T_S * N_NODES * OUT_F * 2 : (size_t)N_NODES * OUT_F * 2);

    hipMemsetAsync(cnt, 0, (size_t)N_NODES * 4, stream);
    k_count<<<N_EDGES / 256, 256, 0, stream>>>(dst, cnt);
    k_scan<<<1, 1024, 0, stream>>>(cnt, row_ptr, cursor);
    k_fill<<<N_EDGES / 256, 256, 0, stream>>>(src, dst, ew, cursor, csr_src, csr_w);
    k_spmm1<<<N_NODES / 2, 256, 0, stream>>>(x, row_ptr, csr_src, csr_w, agg1);
    k_wprep<<<(T_S * 20480) / 256, 256, 0, stream>>>(W1, W2, m1, m2, wf);

    if (batched) {
        k_gemm<<<dim3(782, 8), 256, 0, stream>>>(agg1, wf, P, 0);
        k_spmm2<<<N_NODES, 512, 0, stream>>>(P, row_ptr, csr_src, csr_w, out);
    } else {
        for (int t = 0; t < T_S; t++) {
            k_gemm<<<dim3(782, 1), 256, 0, stream>>>(agg1, wf, P, t);
            k_spmm2_1t<<<6250, 512, 0, stream>>>(P, row_ptr, csr_src, csr_w,
                                                 out + (size_t)t * N_NODES * OUT_F);
        }
    }
}

// Round 2
// 547.958 us; speedup vs baseline: 1.1368x; 1.1368x over previous
//
#include <hip/hip_runtime.h>

#define N_NODES 50000
#define N_EDGES 800000
#define IN_F 96
#define HID_F 128
#define OUT_F 64
#define T_S 8

typedef __attribute__((ext_vector_type(8))) short short8;
typedef __attribute__((ext_vector_type(4))) float float4v;

__device__ __forceinline__ float bf2f(unsigned short h) {
    unsigned u = ((unsigned)h) << 16;
    float f;
    __builtin_memcpy(&f, &u, 4);
    return f;
}
__device__ __forceinline__ unsigned short f2bf(float f) {
    unsigned u;
    __builtin_memcpy(&u, &f, 4);
    unsigned r = (u + 0x7fffu + ((u >> 16) & 1u)) >> 16;  // RTNE
    return (unsigned short)r;
}
__device__ __forceinline__ float bf_lo(unsigned u) {
    unsigned v = u << 16;
    float f;
    __builtin_memcpy(&f, &v, 4);
    return f;
}
__device__ __forceinline__ float bf_hi(unsigned u) {
    unsigned v = u & 0xffff0000u;
    float f;
    __builtin_memcpy(&f, &v, 4);
    return f;
}

// ---------------- CSR build ----------------
__global__ void k_count(const int* __restrict__ dst, int* __restrict__ cnt) {
    int e = blockIdx.x * 256 + threadIdx.x;
    if (e < N_EDGES) atomicAdd(&cnt[dst[e]], 1);
}

__global__ void k_scan(const int* __restrict__ cnt, int* __restrict__ row_ptr,
                       int* __restrict__ cursor) {
    __shared__ int buf[1024];
    const int CH = 49;  // 1024*49 = 50176 >= 50000
    int tid = threadIdx.x;
    int base = tid * CH;
    int s = 0;
    for (int i = 0; i < CH; i++) {
        int idx = base + i;
        if (idx < N_NODES) s += cnt[idx];
    }
    buf[tid] = s;
    __syncthreads();
    for (int off = 1; off < 1024; off <<= 1) {
        int v = buf[tid];
        if (tid >= off) v += buf[tid - off];
        __syncthreads();
        buf[tid] = v;
        __syncthreads();
    }
    int p = (tid == 0) ? 0 : buf[tid - 1];  // exclusive prefix
    for (int i = 0; i < CH; i++) {
        int idx = base + i;
        if (idx < N_NODES) {
            row_ptr[idx] = p;
            cursor[idx] = p;
            p += cnt[idx];
        }
    }
    if (tid == 0) row_ptr[N_NODES] = N_EDGES;
}

__global__ void k_fill(const int* __restrict__ src, const int* __restrict__ dst,
                       const float* __restrict__ ew, int* __restrict__ cursor,
                       int* __restrict__ csr_src, float* __restrict__ csr_w) {
    int e = blockIdx.x * 256 + threadIdx.x;
    if (e < N_EDGES) {
        int d = dst[e];
        int pos = atomicAdd(&cursor[d], 1);
        csr_src[pos] = src[e];
        csr_w[pos] = ew[e];
    }
}

// ---------------- x -> bf16 copy ----------------
__global__ void k_xb(const float* __restrict__ x, unsigned short* __restrict__ xb) {
    int i = blockIdx.x * 256 + threadIdx.x;
    int idx = i * 4;
    if (idx < N_NODES * IN_F) {
        float4 v = *(const float4*)(x + idx);
        uint2 r;
        r.x = (unsigned)f2bf(v.x) | ((unsigned)f2bf(v.y) << 16);
        r.y = (unsigned)f2bf(v.z) | ((unsigned)f2bf(v.w) << 16);
        *(uint2*)(xb + idx) = r;
    }
}

// ---------------- SPMM1: agg1 = spmm(xb), wave per node, dword gathers, unroll 8 ----------------
__global__ __launch_bounds__(256) void k_spmm1(const unsigned short* __restrict__ xb,
                                               const int* __restrict__ row_ptr,
                                               const int* __restrict__ csr_src,
                                               const float* __restrict__ csr_w,
                                               unsigned short* __restrict__ agg1) {
    int wave = threadIdx.x >> 6, lane = threadIdx.x & 63;
    int node = blockIdx.x * 4 + wave;
    if (lane >= 48) return;  // 48 dwords per 96-bf16 row
    int beg = row_ptr[node], end = row_ptr[node + 1];
    const unsigned* xrow = (const unsigned*)xb;
    float a0 = 0.f, a1 = 0.f;
    int e = beg;
    for (; e + 7 < end; e += 8) {
        int s[8];
        float wv[8];
        unsigned d[8];
#pragma unroll
        for (int i = 0; i < 8; i++) {
            s[i] = csr_src[e + i];
            wv[i] = csr_w[e + i];
        }
#pragma unroll
        for (int i = 0; i < 8; i++) d[i] = xrow[(size_t)s[i] * 48 + lane];
#pragma unroll
        for (int i = 0; i < 8; i++) {
            a0 = fmaf(wv[i], bf_lo(d[i]), a0);
            a1 = fmaf(wv[i], bf_hi(d[i]), a1);
        }
    }
    for (; e < end; e++) {
        int s = csr_src[e];
        float wv = csr_w[e];
        unsigned d = xrow[(size_t)s * 48 + lane];
        a0 = fmaf(wv, bf_lo(d), a0);
        a1 = fmaf(wv, bf_hi(d), a1);
    }
    ((unsigned*)agg1)[(size_t)node * 48 + lane] =
        (unsigned)f2bf(a0) | ((unsigned)f2bf(a1) << 16);
}

// ------------- Weight prep: masked W1/W2 pre-swizzled into MFMA fragment order -------------
__global__ void k_wprep(const float* __restrict__ W1, const float* __restrict__ W2,
                        const float* __restrict__ m1, const float* __restrict__ m2,
                        unsigned short* __restrict__ wf) {
    int gid = blockIdx.x * 256 + threadIdx.x;  // 8*20480 = 163840 total
    if (gid >= T_S * 20480) return;
    int t = gid / 20480;
    int idx = gid % 20480;
    float val;
    if (idx < 12288) {
        int j = idx & 7, lane = (idx >> 3) & 63, fr = idx >> 9;  // fr 0..23
        int kk = fr >> 3, nt = fr & 7;
        int k = kk * 32 + (lane >> 4) * 8 + j;
        int n = nt * 16 + (lane & 15);
        val = W1[k * HID_F + n] * m1[((size_t)t * IN_F + k) * HID_F + n];
    } else {
        int i2 = idx - 12288;
        int j = i2 & 7, lane = (i2 >> 3) & 63, fr = i2 >> 9;  // fr 0..15
        int kk = fr >> 2, ot = fr & 3;
        int k = kk * 32 + (lane >> 4) * 8 + j;
        int o = ot * 16 + (lane & 15);
        val = W2[k * OUT_F + o] * m2[((size_t)t * HID_F + k) * OUT_F + o];
    }
    wf[gid] = f2bf(val);
}

// ------------- Fused GEMM: p_t = relu(agg1 @ W1m_t) @ W2m_t, bf16 out, layout per flags -------------
__global__ __launch_bounds__(256) void k_gemm(const unsigned short* __restrict__ agg1,
                                              const unsigned short* __restrict__ wfrags,
                                              unsigned short* __restrict__ P, int tBase,
                                              int nodeStride, int tMul) {
    __shared__ __align__(16) unsigned short ldsW[20480];     // 40 KB
    __shared__ __align__(16) unsigned short ldsH[4][2176];   // 4 waves x [16][136] bf16
    int t = tBase + blockIdx.y;
    const uint4* wsrc = (const uint4*)(wfrags + (size_t)t * 20480);
    uint4* wdst = (uint4*)ldsW;
    for (int i = threadIdx.x; i < 2560; i += 256) wdst[i] = wsrc[i];
    __syncthreads();

    int wave = threadIdx.x >> 6, lane = threadIdx.x & 63;
    int quad = lane >> 4, l15 = lane & 15;
    int node = blockIdx.x * 64 + wave * 16 + l15;
    bool v = node < N_NODES;

    short8 a[3];
    if (v) {
        const unsigned short* ap = agg1 + (size_t)node * IN_F;
        a[0] = *(const short8*)(ap + 0 * 32 + quad * 8);
        a[1] = *(const short8*)(ap + 1 * 32 + quad * 8);
        a[2] = *(const short8*)(ap + 2 * 32 + quad * 8);
    } else {
        short8 z = {0, 0, 0, 0, 0, 0, 0, 0};
        a[0] = z; a[1] = z; a[2] = z;
    }

    for (int nt = 0; nt < 8; nt++) {
        float4v acc = {0.f, 0.f, 0.f, 0.f};
        for (int kk = 0; kk < 3; kk++) {
            short8 w = *(const short8*)&ldsW[(kk * 8 + nt) * 512 + lane * 8];
            acc = __builtin_amdgcn_mfma_f32_16x16x32_bf16(w, a[kk], acc, 0, 0, 0);
        }
        unsigned h0 = f2bf(fmaxf(acc[0], 0.f));
        unsigned h1 = f2bf(fmaxf(acc[1], 0.f));
        unsigned h2 = f2bf(fmaxf(acc[2], 0.f));
        unsigned h3 = f2bf(fmaxf(acc[3], 0.f));
        uint2 pk;
        pk.x = h0 | (h1 << 16);
        pk.y = h2 | (h3 << 16);
        *(uint2*)&ldsH[wave][l15 * 136 + nt * 16 + quad * 4] = pk;
    }

    short8 hf[4];
    for (int kk = 0; kk < 4; kk++)
        hf[kk] = *(const short8*)&ldsH[wave][l15 * 136 + kk * 32 + quad * 8];

    unsigned short* Pt = P + (size_t)node * nodeStride + (size_t)t * tMul;
    for (int ot = 0; ot < 4; ot++) {
        float4v acc = {0.f, 0.f, 0.f, 0.f};
        for (int kk = 0; kk < 4; kk++) {
            short8 w = *(const short8*)&ldsW[12288 + (kk * 4 + ot) * 512 + lane * 8];
            acc = __builtin_amdgcn_mfma_f32_16x16x32_bf16(w, hf[kk], acc, 0, 0, 0);
        }
        if (v) {
            uint2 pk;
            pk.x = (unsigned)f2bf(acc[0]) | ((unsigned)f2bf(acc[1]) << 16);
            pk.y = (unsigned)f2bf(acc[2]) | ((unsigned)f2bf(acc[3]) << 16);
            *(uint2*)(Pt + ot * 16 + quad * 4) = pk;
        }
    }
}

// ------------- SPMM2 batched: P layout [node][t][o] (512 bf16 = 1KB/row), wave per node -------------
__global__ __launch_bounds__(256) void k_spmm2(const unsigned short* __restrict__ P,
                                               const int* __restrict__ row_ptr,
                                               const int* __restrict__ csr_src,
                                               const float* __restrict__ csr_w,
                                               float* __restrict__ out) {
    int wave = threadIdx.x >> 6, lane = threadIdx.x & 63;
    int node = blockIdx.x * 4 + wave;
    int beg = row_ptr[node], end = row_ptr[node + 1];
    const uint4* Pl = (const uint4*)P + lane;  // row = 64 uint4
    float acc[8] = {0.f, 0.f, 0.f, 0.f, 0.f, 0.f, 0.f, 0.f};
    int e = beg;
    for (; e + 7 < end; e += 8) {
        int s[8];
        float wv[8];
        uint4 d[8];
#pragma unroll
        for (int i = 0; i < 8; i++) {
            s[i] = csr_src[e + i];
            wv[i] = csr_w[e + i];
        }
#pragma unroll
        for (int i = 0; i < 8; i++) d[i] = Pl[(size_t)s[i] * 64];
#pragma unroll
        for (int i = 0; i < 8; i++) {
            acc[0] = fmaf(wv[i], bf_lo(d[i].x), acc[0]);
            acc[1] = fmaf(wv[i], bf_hi(d[i].x), acc[1]);
            acc[2] = fmaf(wv[i], bf_lo(d[i].y), acc[2]);
            acc[3] = fmaf(wv[i], bf_hi(d[i].y), acc[3]);
            acc[4] = fmaf(wv[i], bf_lo(d[i].z), acc[4]);
            acc[5] = fmaf(wv[i], bf_hi(d[i].z), acc[5]);
            acc[6] = fmaf(wv[i], bf_lo(d[i].w), acc[6]);
            acc[7] = fmaf(wv[i], bf_hi(d[i].w), acc[7]);
        }
    }
    for (; e < end; e++) {
        int s = csr_src[e];
        float wv = csr_w[e];
        uint4 d = Pl[(size_t)s * 64];
        acc[0] = fmaf(wv, bf_lo(d.x), acc[0]);
        acc[1] = fmaf(wv, bf_hi(d.x), acc[1]);
        acc[2] = fmaf(wv, bf_lo(d.y), acc[2]);
        acc[3] = fmaf(wv, bf_hi(d.y), acc[3]);
        acc[4] = fmaf(wv, bf_lo(d.z), acc[4]);
        acc[5] = fmaf(wv, bf_hi(d.z), acc[5]);
        acc[6] = fmaf(wv, bf_lo(d.w), acc[6]);
        acc[7] = fmaf(wv, bf_hi(d.w), acc[7]);
    }
    // lane covers value indices lane*8..+7 of the [t][o] row: t = lane>>3, o = (lane&7)*8
    int t = lane >> 3, o = (lane & 7) * 8;
    float* op = out + ((size_t)t * N_NODES + node) * OUT_F + o;
    float4 v0 = {acc[0], acc[1], acc[2], acc[3]};
    float4 v1 = {acc[4], acc[5], acc[6], acc[7]};
    *(float4*)op = v0;
    *(float4*)(op + 4) = v1;
}

// per-sample fallback (small workspace): P layout [node][64]
__global__ __launch_bounds__(512) void k_spmm2_1t(const unsigned short* __restrict__ P,
                                                  const int* __restrict__ row_ptr,
                                                  const int* __restrict__ csr_src,
                                                  const float* __restrict__ csr_w,
                                                  float* __restrict__ out) {
    int node = blockIdx.x * 8 + (threadIdx.x >> 6);
    int o = threadIdx.x & 63;
    if (node >= N_NODES) return;
    int beg = row_ptr[node], end = row_ptr[node + 1];
    const unsigned short* Pt = P + o;
    float a0 = 0.f, a1 = 0.f, a2 = 0.f, a3 = 0.f;
    int e = beg;
    for (; e + 3 < end; e += 4) {
        int s0 = csr_src[e], s1 = csr_src[e + 1], s2 = csr_src[e + 2], s3 = csr_src[e + 3];
        float w0 = csr_w[e], w1 = csr_w[e + 1], w2 = csr_w[e + 2], w3 = csr_w[e + 3];
        a0 += w0 * bf2f(Pt[(size_t)s0 * OUT_F]);
        a1 += w1 * bf2f(Pt[(size_t)s1 * OUT_F]);
        a2 += w2 * bf2f(Pt[(size_t)s2 * OUT_F]);
        a3 += w3 * bf2f(Pt[(size_t)s3 * OUT_F]);
    }
    for (; e < end; e++) a0 += csr_w[e] * bf2f(Pt[(size_t)csr_src[e] * OUT_F]);
    out[(size_t)node * OUT_F + o] = a0 + a1 + a2 + a3;
}

extern "C" void kernel_launch(void* const* d_in, const int* in_sizes, int n_in,
                              void* d_out, int out_size, void* d_ws, size_t ws_size,
                              hipStream_t stream) {
    const float* x = (const float*)d_in[0];
    const float* ew = (const float*)d_in[1];
    const float* W1 = (const float*)d_in[2];
    const float* W2 = (const float*)d_in[3];
    const float* m1 = (const float*)d_in[4];
    const float* m2 = (const float*)d_in[5];
    const int* src = (const int*)d_in[6];
    const int* dst = (const int*)d_in[7];
    float* out = (float*)d_out;

    char* w = (char*)d_ws;
    size_t off = 0;
    auto alloc = [&](size_t bytes) -> void* {
        void* p = (void*)(w + off);
        off += (bytes + 255) & ~(size_t)255;
        return p;
    };
    int* cnt = (int*)alloc((size_t)N_NODES * 4);
    int* row_ptr = (int*)alloc((size_t)(N_NODES + 1) * 4);
    int* cursor = (int*)alloc((size_t)N_NODES * 4);
    int* csr_src = (int*)alloc((size_t)N_EDGES * 4);
    float* csr_w = (float*)alloc((size_t)N_EDGES * 4);
    unsigned short* agg1 = (unsigned short*)alloc((size_t)N_NODES * IN_F * 2);
    unsigned short* wf = (unsigned short*)alloc((size_t)T_S * 20480 * 2);

    // union region: xb (9.6 MB, dead before k_gemm) overlaps P (51.2 MB batched)
    size_t unionBase = off;
    size_t pBytesBatched = (size_t)T_S * N_NODES * OUT_F * 2;
    size_t xbBytes = (size_t)N_NODES * IN_F * 2;
    size_t pBytes1t = (size_t)N_NODES * OUT_F * 2;
    bool batched = ws_size >= unionBase + (pBytesBatched > xbBytes ? pBytesBatched : xbBytes);
    unsigned short* xb = (unsigned short*)(w + unionBase);
    unsigned short* P = (unsigned short*)(w + unionBase);
    if (!batched) {
        // need xb and P(6.4MB) disjoint
        xb = (unsigned short*)(w + unionBase);
        P = (unsigned short*)(w + unionBase + ((xbBytes + 255) & ~(size_t)255));
        (void)pBytes1t;
    }

    hipMemsetAsync(cnt, 0, (size_t)N_NODES * 4, stream);
    k_count<<<N_EDGES / 256, 256, 0, stream>>>(dst, cnt);
    k_scan<<<1, 1024, 0, stream>>>(cnt, row_ptr, cursor);
    k_fill<<<N_EDGES / 256, 256, 0, stream>>>(src, dst, ew, cursor, csr_src, csr_w);
    k_xb<<<(N_NODES * IN_F / 4 + 255) / 256, 256, 0, stream>>>(x, xb);
    k_spmm1<<<N_NODES / 4, 256, 0, stream>>>(xb, row_ptr, csr_src, csr_w, agg1);
    k_wprep<<<(T_S * 20480) / 256, 256, 0, stream>>>(W1, W2, m1, m2, wf);

    if (batched) {
        k_gemm<<<dim3(782, 8), 256, 0, stream>>>(agg1, wf, P, 0, T_S * OUT_F, OUT_F);
        k_spmm2<<<N_NODES / 4, 256, 0, stream>>>(P, row_ptr, csr_src, csr_w, out);
    } else {
        for (int t = 0; t < T_S; t++) {
            k_gemm<<<dim3(782, 1), 256, 0, stream>>>(agg1, wf, P, t, OUT_F, 0);
            k_spmm2_1t<<<6250, 512, 0, stream>>>(P, row_ptr, csr_src, csr_w,
                                                 out + (size_t)t * N_NODES * OUT_F);
        }
    }
}

// Round 3
// 432.580 us; speedup vs baseline: 1.4400x; 1.2667x over previous
//
#include <hip/hip_runtime.h>

#define N_NODES 50000
#define N_EDGES 800000
#define IN_F 96
#define HID_F 128
#define OUT_F 64
#define T_S 8
#define SCAN_B 196  // ceil(50000/256)

typedef __attribute__((ext_vector_type(8))) short short8;
typedef __attribute__((ext_vector_type(4))) float float4v;

__device__ __forceinline__ float bf2f(unsigned short h) {
    unsigned u = ((unsigned)h) << 16;
    float f;
    __builtin_memcpy(&f, &u, 4);
    return f;
}
__device__ __forceinline__ unsigned short f2bf(float f) {
    unsigned u;
    __builtin_memcpy(&u, &f, 4);
    unsigned r = (u + 0x7fffu + ((u >> 16) & 1u)) >> 16;  // RTNE
    return (unsigned short)r;
}
__device__ __forceinline__ float bf_lo(unsigned u) {
    unsigned v = u << 16;
    float f;
    __builtin_memcpy(&f, &v, 4);
    return f;
}
__device__ __forceinline__ float bf_hi(unsigned u) {
    unsigned v = u & 0xffff0000u;
    float f;
    __builtin_memcpy(&f, &v, 4);
    return f;
}

// ---------------- CSR build ----------------
__global__ void k_count(const int* __restrict__ dst, int* __restrict__ cnt) {
    int e = blockIdx.x * 256 + threadIdx.x;
    if (e < N_EDGES) atomicAdd(&cnt[dst[e]], 1);
}

// hierarchical scan, stage 1: per-block inclusive scan of 256 counts
__global__ __launch_bounds__(256) void k_scan1(const int* __restrict__ cnt,
                                               int* __restrict__ excl,
                                               int* __restrict__ blockSums) {
    __shared__ int buf[256];
    int tid = threadIdx.x;
    int idx = blockIdx.x * 256 + tid;
    int v = (idx < N_NODES) ? cnt[idx] : 0;
    buf[tid] = v;
    __syncthreads();
    for (int off = 1; off < 256; off <<= 1) {
        int t = buf[tid];
        int u = (tid >= off) ? buf[tid - off] : 0;
        __syncthreads();
        buf[tid] = t + u;
        __syncthreads();
    }
    int incl = buf[tid];
    if (idx < N_NODES) excl[idx] = incl - v;  // exclusive within block
    if (tid == 255) blockSums[blockIdx.x] = incl;
}

// stage 2: one block scans the 196 block sums -> exclusive block offsets
__global__ __launch_bounds__(256) void k_scan2(const int* __restrict__ blockSums,
                                               int* __restrict__ blockOff) {
    __shared__ int buf[256];
    int tid = threadIdx.x;
    int v = (tid < SCAN_B) ? blockSums[tid] : 0;
    buf[tid] = v;
    __syncthreads();
    for (int off = 1; off < 256; off <<= 1) {
        int t = buf[tid];
        int u = (tid >= off) ? buf[tid - off] : 0;
        __syncthreads();
        buf[tid] = t + u;
        __syncthreads();
    }
    if (tid < SCAN_B) blockOff[tid] = buf[tid] - v;
}

// stage 3: combine -> row_ptr, cursor
__global__ __launch_bounds__(256) void k_scan3(const int* __restrict__ excl,
                                               const int* __restrict__ blockOff,
                                               int* __restrict__ row_ptr,
                                               int* __restrict__ cursor) {
    int idx = blockIdx.x * 256 + threadIdx.x;
    if (idx < N_NODES) {
        int p = excl[idx] + blockOff[blockIdx.x];
        row_ptr[idx] = p;
        cursor[idx] = p;
    }
    if (idx == 0) row_ptr[N_NODES] = N_EDGES;
}

__global__ void k_fill(const int* __restrict__ src, const int* __restrict__ dst,
                       const float* __restrict__ ew, int* __restrict__ cursor,
                       int* __restrict__ csr_src, float* __restrict__ csr_w) {
    int e = blockIdx.x * 256 + threadIdx.x;
    if (e < N_EDGES) {
        int d = dst[e];
        int pos = atomicAdd(&cursor[d], 1);
        csr_src[pos] = src[e];
        csr_w[pos] = ew[e];
    }
}

// ---------------- x -> bf16 copy ----------------
__global__ void k_xb(const float* __restrict__ x, unsigned short* __restrict__ xb) {
    int i = blockIdx.x * 256 + threadIdx.x;
    int idx = i * 4;
    if (idx < N_NODES * IN_F) {
        float4 v = *(const float4*)(x + idx);
        uint2 r;
        r.x = (unsigned)f2bf(v.x) | ((unsigned)f2bf(v.y) << 16);
        r.y = (unsigned)f2bf(v.z) | ((unsigned)f2bf(v.w) << 16);
        *(uint2*)(xb + idx) = r;
    }
}

// ---------------- SPMM1: agg1 = spmm(xb), wave per node, dword gathers, unroll 8 ----------------
__global__ __launch_bounds__(256) void k_spmm1(const unsigned short* __restrict__ xb,
                                               const int* __restrict__ row_ptr,
                                               const int* __restrict__ csr_src,
                                               const float* __restrict__ csr_w,
                                               unsigned short* __restrict__ agg1) {
    int wave = threadIdx.x >> 6, lane = threadIdx.x & 63;
    int node = blockIdx.x * 4 + wave;
    if (lane >= 48) return;  // 48 dwords per 96-bf16 row
    int beg = row_ptr[node], end = row_ptr[node + 1];
    const unsigned* xrow = (const unsigned*)xb;
    float a0 = 0.f, a1 = 0.f;
    int e = beg;
    for (; e + 7 < end; e += 8) {
        int s[8];
        float wv[8];
        unsigned d[8];
#pragma unroll
        for (int i = 0; i < 8; i++) {
            s[i] = csr_src[e + i];
            wv[i] = csr_w[e + i];
        }
#pragma unroll
        for (int i = 0; i < 8; i++) d[i] = xrow[(size_t)s[i] * 48 + lane];
#pragma unroll
        for (int i = 0; i < 8; i++) {
            a0 = fmaf(wv[i], bf_lo(d[i]), a0);
            a1 = fmaf(wv[i], bf_hi(d[i]), a1);
        }
    }
    for (; e < end; e++) {
        int s = csr_src[e];
        float wv = csr_w[e];
        unsigned d = xrow[(size_t)s * 48 + lane];
        a0 = fmaf(wv, bf_lo(d), a0);
        a1 = fmaf(wv, bf_hi(d), a1);
    }
    ((unsigned*)agg1)[(size_t)node * 48 + lane] =
        (unsigned)f2bf(a0) | ((unsigned)f2bf(a1) << 16);
}

// ------------- Weight prep: masked W1/W2 pre-swizzled into MFMA fragment order -------------
__global__ void k_wprep(const float* __restrict__ W1, const float* __restrict__ W2,
                        const float* __restrict__ m1, const float* __restrict__ m2,
                        unsigned short* __restrict__ wf) {
    int gid = blockIdx.x * 256 + threadIdx.x;  // 8*20480 = 163840 total
    if (gid >= T_S * 20480) return;
    int t = gid / 20480;
    int idx = gid % 20480;
    float val;
    if (idx < 12288) {
        int j = idx & 7, lane = (idx >> 3) & 63, fr = idx >> 9;  // fr 0..23
        int kk = fr >> 3, nt = fr & 7;
        int k = kk * 32 + (lane >> 4) * 8 + j;
        int n = nt * 16 + (lane & 15);
        val = W1[k * HID_F + n] * m1[((size_t)t * IN_F + k) * HID_F + n];
    } else {
        int i2 = idx - 12288;
        int j = i2 & 7, lane = (i2 >> 3) & 63, fr = i2 >> 9;  // fr 0..15
        int kk = fr >> 2, ot = fr & 3;
        int k = kk * 32 + (lane >> 4) * 8 + j;
        int o = ot * 16 + (lane & 15);
        val = W2[k * OUT_F + o] * m2[((size_t)t * HID_F + k) * OUT_F + o];
    }
    wf[gid] = f2bf(val);
}

// ------------- Fused GEMM: p_t = relu(agg1 @ W1m_t) @ W2m_t, bf16 out, layout per flags -------------
__global__ __launch_bounds__(256) void k_gemm(const unsigned short* __restrict__ agg1,
                                              const unsigned short* __restrict__ wfrags,
                                              unsigned short* __restrict__ P, int tBase,
                                              int nodeStride, int tMul) {
    __shared__ __align__(16) unsigned short ldsW[20480];     // 40 KB
    __shared__ __align__(16) unsigned short ldsH[4][2176];   // 4 waves x [16][136] bf16
    int t = tBase + blockIdx.y;
    const uint4* wsrc = (const uint4*)(wfrags + (size_t)t * 20480);
    uint4* wdst = (uint4*)ldsW;
    for (int i = threadIdx.x; i < 2560; i += 256) wdst[i] = wsrc[i];
    __syncthreads();

    int wave = threadIdx.x >> 6, lane = threadIdx.x & 63;
    int quad = lane >> 4, l15 = lane & 15;
    int node = blockIdx.x * 64 + wave * 16 + l15;
    bool v = node < N_NODES;

    short8 a[3];
    if (v) {
        const unsigned short* ap = agg1 + (size_t)node * IN_F;
        a[0] = *(const short8*)(ap + 0 * 32 + quad * 8);
        a[1] = *(const short8*)(ap + 1 * 32 + quad * 8);
        a[2] = *(const short8*)(ap + 2 * 32 + quad * 8);
    } else {
        short8 z = {0, 0, 0, 0, 0, 0, 0, 0};
        a[0] = z; a[1] = z; a[2] = z;
    }

    for (int nt = 0; nt < 8; nt++) {
        float4v acc = {0.f, 0.f, 0.f, 0.f};
        for (int kk = 0; kk < 3; kk++) {
            short8 w = *(const short8*)&ldsW[(kk * 8 + nt) * 512 + lane * 8];
            acc = __builtin_amdgcn_mfma_f32_16x16x32_bf16(w, a[kk], acc, 0, 0, 0);
        }
        unsigned h0 = f2bf(fmaxf(acc[0], 0.f));
        unsigned h1 = f2bf(fmaxf(acc[1], 0.f));
        unsigned h2 = f2bf(fmaxf(acc[2], 0.f));
        unsigned h3 = f2bf(fmaxf(acc[3], 0.f));
        uint2 pk;
        pk.x = h0 | (h1 << 16);
        pk.y = h2 | (h3 << 16);
        *(uint2*)&ldsH[wave][l15 * 136 + nt * 16 + quad * 4] = pk;
    }

    short8 hf[4];
    for (int kk = 0; kk < 4; kk++)
        hf[kk] = *(const short8*)&ldsH[wave][l15 * 136 + kk * 32 + quad * 8];

    unsigned short* Pt = P + (size_t)node * nodeStride + (size_t)t * tMul;
    for (int ot = 0; ot < 4; ot++) {
        float4v acc = {0.f, 0.f, 0.f, 0.f};
        for (int kk = 0; kk < 4; kk++) {
            short8 w = *(const short8*)&ldsW[12288 + (kk * 4 + ot) * 512 + lane * 8];
            acc = __builtin_amdgcn_mfma_f32_16x16x32_bf16(w, hf[kk], acc, 0, 0, 0);
        }
        if (v) {
            uint2 pk;
            pk.x = (unsigned)f2bf(acc[0]) | ((unsigned)f2bf(acc[1]) << 16);
            pk.y = (unsigned)f2bf(acc[2]) | ((unsigned)f2bf(acc[3]) << 16);
            *(uint2*)(Pt + ot * 16 + quad * 4) = pk;
        }
    }
}

// ------------- SPMM2 batched: P layout [node][t][o] (512 bf16 = 1KB/row), wave per node -------------
__global__ __launch_bounds__(256) void k_spmm2(const unsigned short* __restrict__ P,
                                               const int* __restrict__ row_ptr,
                                               const int* __restrict__ csr_src,
                                               const float* __restrict__ csr_w,
                                               float* __restrict__ out) {
    int wave = threadIdx.x >> 6, lane = threadIdx.x & 63;
    int node = blockIdx.x * 4 + wave;
    int beg = row_ptr[node], end = row_ptr[node + 1];
    const uint4* Pl = (const uint4*)P + lane;  // row = 64 uint4
    float acc[8] = {0.f, 0.f, 0.f, 0.f, 0.f, 0.f, 0.f, 0.f};
    int e = beg;
    for (; e + 7 < end; e += 8) {
        int s[8];
        float wv[8];
        uint4 d[8];
#pragma unroll
        for (int i = 0; i < 8; i++) {
            s[i] = csr_src[e + i];
            wv[i] = csr_w[e + i];
        }
#pragma unroll
        for (int i = 0; i < 8; i++) d[i] = Pl[(size_t)s[i] * 64];
#pragma unroll
        for (int i = 0; i < 8; i++) {
            acc[0] = fmaf(wv[i], bf_lo(d[i].x), acc[0]);
            acc[1] = fmaf(wv[i], bf_hi(d[i].x), acc[1]);
            acc[2] = fmaf(wv[i], bf_lo(d[i].y), acc[2]);
            acc[3] = fmaf(wv[i], bf_hi(d[i].y), acc[3]);
            acc[4] = fmaf(wv[i], bf_lo(d[i].z), acc[4]);
            acc[5] = fmaf(wv[i], bf_hi(d[i].z), acc[5]);
            acc[6] = fmaf(wv[i], bf_lo(d[i].w), acc[6]);
            acc[7] = fmaf(wv[i], bf_hi(d[i].w), acc[7]);
        }
    }
    for (; e < end; e++) {
        int s = csr_src[e];
        float wv = csr_w[e];
        uint4 d = Pl[(size_t)s * 64];
        acc[0] = fmaf(wv, bf_lo(d.x), acc[0]);
        acc[1] = fmaf(wv, bf_hi(d.x), acc[1]);
        acc[2] = fmaf(wv, bf_lo(d.y), acc[2]);
        acc[3] = fmaf(wv, bf_hi(d.y), acc[3]);
        acc[4] = fmaf(wv, bf_lo(d.z), acc[4]);
        acc[5] = fmaf(wv, bf_hi(d.z), acc[5]);
        acc[6] = fmaf(wv, bf_lo(d.w), acc[6]);
        acc[7] = fmaf(wv, bf_hi(d.w), acc[7]);
    }
    // lane covers value indices lane*8..+7 of the [t][o] row: t = lane>>3, o = (lane&7)*8
    int t = lane >> 3, o = (lane & 7) * 8;
    float* op = out + ((size_t)t * N_NODES + node) * OUT_F + o;
    float4 v0 = {acc[0], acc[1], acc[2], acc[3]};
    float4 v1 = {acc[4], acc[5], acc[6], acc[7]};
    *(float4*)op = v0;
    *(float4*)(op + 4) = v1;
}

// per-sample fallback (small workspace): P layout [node][64]
__global__ __launch_bounds__(512) void k_spmm2_1t(const unsigned short* __restrict__ P,
                                                  const int* __restrict__ row_ptr,
                                                  const int* __restrict__ csr_src,
                                                  const float* __restrict__ csr_w,
                                                  float* __restrict__ out) {
    int node = blockIdx.x * 8 + (threadIdx.x >> 6);
    int o = threadIdx.x & 63;
    if (node >= N_NODES) return;
    int beg = row_ptr[node], end = row_ptr[node + 1];
    const unsigned short* Pt = P + o;
    float a0 = 0.f, a1 = 0.f, a2 = 0.f, a3 = 0.f;
    int e = beg;
    for (; e + 3 < end; e += 4) {
        int s0 = csr_src[e], s1 = csr_src[e + 1], s2 = csr_src[e + 2], s3 = csr_src[e + 3];
        float w0 = csr_w[e], w1 = csr_w[e + 1], w2 = csr_w[e + 2], w3 = csr_w[e + 3];
        a0 += w0 * bf2f(Pt[(size_t)s0 * OUT_F]);
        a1 += w1 * bf2f(Pt[(size_t)s1 * OUT_F]);
        a2 += w2 * bf2f(Pt[(size_t)s2 * OUT_F]);
        a3 += w3 * bf2f(Pt[(size_t)s3 * OUT_F]);
    }
    for (; e < end; e++) a0 += csr_w[e] * bf2f(Pt[(size_t)csr_src[e] * OUT_F]);
    out[(size_t)node * OUT_F + o] = a0 + a1 + a2 + a3;
}

extern "C" void kernel_launch(void* const* d_in, const int* in_sizes, int n_in,
                              void* d_out, int out_size, void* d_ws, size_t ws_size,
                              hipStream_t stream) {
    const float* x = (const float*)d_in[0];
    const float* ew = (const float*)d_in[1];
    const float* W1 = (const float*)d_in[2];
    const float* W2 = (const float*)d_in[3];
    const float* m1 = (const float*)d_in[4];
    const float* m2 = (const float*)d_in[5];
    const int* src = (const int*)d_in[6];
    const int* dst = (const int*)d_in[7];
    float* out = (float*)d_out;

    char* w = (char*)d_ws;
    size_t off = 0;
    auto alloc = [&](size_t bytes) -> void* {
        void* p = (void*)(w + off);
        off += (bytes + 255) & ~(size_t)255;
        return p;
    };
    int* cnt = (int*)alloc((size_t)N_NODES * 4);
    int* row_ptr = (int*)alloc((size_t)(N_NODES + 1) * 4);
    int* cursor = (int*)alloc((size_t)N_NODES * 4);
    int* excl = (int*)alloc((size_t)N_NODES * 4);
    int* blockSums = (int*)alloc((size_t)SCAN_B * 4);
    int* blockOff = (int*)alloc((size_t)SCAN_B * 4);
    int* csr_src = (int*)alloc((size_t)N_EDGES * 4);
    float* csr_w = (float*)alloc((size_t)N_EDGES * 4);
    unsigned short* agg1 = (unsigned short*)alloc((size_t)N_NODES * IN_F * 2);
    unsigned short* wf = (unsigned short*)alloc((size_t)T_S * 20480 * 2);

    // union region: xb (9.6 MB, dead before k_gemm) overlaps P (51.2 MB batched)
    size_t unionBase = off;
    size_t pBytesBatched = (size_t)T_S * N_NODES * OUT_F * 2;
    size_t xbBytes = (size_t)N_NODES * IN_F * 2;
    bool batched = ws_size >= unionBase + (pBytesBatched > xbBytes ? pBytesBatched : xbBytes);
    unsigned short* xb = (unsigned short*)(w + unionBase);
    unsigned short* P = (unsigned short*)(w + unionBase);
    if (!batched) {
        xb = (unsigned short*)(w + unionBase);
        P = (unsigned short*)(w + unionBase + ((xbBytes + 255) & ~(size_t)255));
    }

    hipMemsetAsync(cnt, 0, (size_t)N_NODES * 4, stream);
    k_count<<<N_EDGES / 256, 256, 0, stream>>>(dst, cnt);
    k_scan1<<<SCAN_B, 256, 0, stream>>>(cnt, excl, blockSums);
    k_scan2<<<1, 256, 0, stream>>>(blockSums, blockOff);
    k_scan3<<<SCAN_B, 256, 0, stream>>>(excl, blockOff, row_ptr, cursor);
    k_fill<<<N_EDGES / 256, 256, 0, stream>>>(src, dst, ew, cursor, csr_src, csr_w);
    k_xb<<<(N_NODES * IN_F / 4 + 255) / 256, 256, 0, stream>>>(x, xb);
    k_spmm1<<<N_NODES / 4, 256, 0, stream>>>(xb, row_ptr, csr_src, csr_w, agg1);
    k_wprep<<<(T_S * 20480) / 256, 256, 0, stream>>>(W1, W2, m1, m2, wf);

    if (batched) {
        k_gemm<<<dim3(782, 8), 256, 0, stream>>>(agg1, wf, P, 0, T_S * OUT_F, OUT_F);
        k_spmm2<<<N_NODES / 4, 256, 0, stream>>>(P, row_ptr, csr_src, csr_w, out);
    } else {
        for (int t = 0; t < T_S; t++) {
            k_gemm<<<dim3(782, 1), 256, 0, stream>>>(agg1, wf, P, t, OUT_F, 0);
            k_spmm2_1t<<<6250, 512, 0, stream>>>(P, row_ptr, csr_src, csr_w,
                                                 out + (size_t)t * N_NODES * OUT_F);
        }
    }
}